// Round 9
// baseline (41.026 us; speedup 1.0000x reference)
//
#include <hip/hip_runtime.h>

typedef float f32x4 __attribute__((ext_vector_type(4)));
typedef short s16x8 __attribute__((ext_vector_type(8)));
typedef unsigned int u32;
typedef unsigned int u32x4 __attribute__((ext_vector_type(4)));
typedef unsigned short u16;

#define DIN 24
#define DH1 64
#define DH2 128
#define DOUT 64

// f32 -> bf16 bits, RNE (setup path)
static __device__ __forceinline__ u16 f2bf(float f) {
    u32 u = __builtin_bit_cast(u32, f);
    u += 0x7FFFu + ((u >> 16) & 1u);
    return (u16)(u >> 16);
}
// packed f32x2 -> bf16x2, one VALU op
static __device__ __forceinline__ u32 cvtpk(float lo, float hi) {
    u32 r;
    asm("v_cvt_pk_bf16_f32 %0, %1, %2" : "=v"(r) : "v"(lo), "v"(hi));
    return r;
}
// cross-lane chunk-transpose primitives (bit-exactness HW-verified in R4)
static __device__ __forceinline__ void swap32(u32& a, u32& b) {
    asm("v_permlane32_swap_b32 %0, %1" : "+v"(a), "+v"(b));
}
static __device__ __forceinline__ void swap16(u32& a, u32& b) {
    asm("v_permlane16_swap_b32 %0, %1" : "+v"(a), "+v"(b));
}

__global__ __launch_bounds__(256, 4) void linenet_r9(
    const float* __restrict__ in,
    const float* __restrict__ W1, const float* __restrict__ b1,
    const float* __restrict__ W2, const float* __restrict__ b2,
    const float* __restrict__ W3, const float* __restrict__ b3,
    float* __restrict__ out, int M)
{
    // ALL weights + biases in LDS (36.75KB/block); minimal persistent VGPR
    // -> 4 blocks/CU = 16 waves/CU. Frag reads are lane-contiguous 16B
    // (2-way = free); bias reads are quadrant-broadcast (free).
    __shared__ __align__(16) u16 w1lds[4 * 64 * 8];    // 4KB  (k=24 row = b1)
    __shared__ __align__(16) u16 w2lds[16 * 64 * 8];   // 16KB (frag = mt*2+ks)
    __shared__ __align__(16) u16 w3lds[16 * 64 * 8];   // 16KB (frag = ks*4+nt)
    __shared__ __align__(16) float b2f[DH2];           // 512B
    __shared__ __align__(16) float b3f[DOUT];          // 256B

    const int tid  = threadIdx.x;
    const int lane = tid & 63;
    const int gl = lane >> 4, cl = lane & 15;

    // ---- build W1^T table: one entry per thread ----
    {
        const int nt = tid >> 6, ln = tid & 63;
        const int g = ln >> 4, c = ln & 15;
        s16x8 v;
        #pragma unroll
        for (int j = 0; j < 8; ++j) {
            const int k = 8 * g + j;
            u16 x = 0;
            if (k < DIN)       x = f2bf(W1[k * DH1 + nt * 16 + c]);
            else if (k == DIN) x = f2bf(b1[nt * 16 + c]);
            v[j] = (short)x;
        }
        *(s16x8*)&w1lds[tid * 8] = v;
    }
    // ---- build W2^T table (frag index = mt*2+ks) ----
    for (int it = tid; it < 16 * 64; it += 256) {
        const int f = it >> 6, ln = it & 63;
        const int mt = f >> 1, ks = f & 1, g = ln >> 4, c = ln & 15;
        s16x8 v;
        #pragma unroll
        for (int j = 0; j < 8; ++j)
            v[j] = (short)f2bf(W2[(32 * ks + 8 * g + j) * DH2 + mt * 16 + c]);
        *(s16x8*)&w2lds[it * 8] = v;
    }
    // ---- build W3^T table (frag index = ks*4+nt) ----
    for (int it = tid; it < 16 * 64; it += 256) {
        const int f = it >> 6, ln = it & 63;
        const int ks = f >> 2, nt = f & 3, g = ln >> 4, c = ln & 15;
        s16x8 v;
        #pragma unroll
        for (int j = 0; j < 8; ++j)
            v[j] = (short)f2bf(W3[(32 * ks + 8 * g + j) * DOUT + nt * 16 + c]);
        *(s16x8*)&w3lds[it * 8] = v;
    }
    // ---- biases as f32 (C-operand loaded via broadcast ds_read_b128) ----
    if (tid < DH2)  b2f[tid] = b2[tid];
    if (tid < DOUT) b3f[tid] = b3[tid];

    __syncthreads();

    const int NT = M / 16;
    const int nw = (int)gridDim.x * 4;
    int t = (int)blockIdx.x * 4 + (tid >> 6);
    if (t >= NT) return;

    // x^T B-frag source: lane (gl,cl) = row cl, 8 floats at 8*gl (gl<3);
    // gl==3: k=24 slot forced to 1.0 (bias row), k=25..31 hit zero weights.
    const int goff = (gl < 3) ? 8 * gl : 0;
    const int loff = cl * DIN + goff;
    const int bo = 4 * gl;   // per-quadrant bias sub-offset

    f32x4 pf0, pf1;
    {
        const float* p = in + (size_t)t * (16 * DIN) + loff;
        pf0 = *(const f32x4*)p;
        pf1 = *(const f32x4*)(p + 4);
    }

    const f32x4 zac = {0.f, 0.f, 0.f, 0.f};

    while (t < NT) {
        // ---- x^T fragment ----
        u32x4 aw;
        aw[0] = cvtpk(pf0[0], pf0[1]);
        aw[1] = cvtpk(pf0[2], pf0[3]);
        aw[2] = cvtpk(pf1[0], pf1[1]);
        aw[3] = cvtpk(pf1[2], pf1[3]);
        if (gl == 3) aw[0] = 0x00003F80u;   // k=24 -> 1.0, k=25 -> 0
        const s16x8 a1 = __builtin_bit_cast(s16x8, aw);

        // ---- prefetch next tile (depth-1) ----
        const int tn = t + nw;
        {
            const int tc = (tn < NT) ? tn : t;
            const float* p = in + (size_t)tc * (16 * DIN) + loff;
            pf0 = *(const f32x4*)p;
            pf1 = *(const f32x4*)(p + 4);
        }

        // ---- layer 1: h1^T = W1^T(+b1 row) * x^T ----
        f32x4 acc1[4];
        #pragma unroll
        for (int nt = 0; nt < 4; ++nt) {
            const s16x8 w1f = *(const s16x8*)&w1lds[(nt * 64 + lane) * 8];
            acc1[nt] = __builtin_amdgcn_mfma_f32_16x16x32_bf16(w1f, a1, zac, 0, 0, 0);
        }

        // relu + pack + in-register transpose
        u32 cw[4][2];
        #pragma unroll
        for (int nt = 0; nt < 4; ++nt) {
            cw[nt][0] = cvtpk(fmaxf(acc1[nt][0], 0.f), fmaxf(acc1[nt][1], 0.f));
            cw[nt][1] = cvtpk(fmaxf(acc1[nt][2], 0.f), fmaxf(acc1[nt][3], 0.f));
        }
        swap32(cw[0][0], cw[1][0]); swap32(cw[0][1], cw[1][1]);
        swap32(cw[2][0], cw[3][0]); swap32(cw[2][1], cw[3][1]);
        swap16(cw[0][0], cw[1][0]); swap16(cw[0][1], cw[1][1]);
        swap16(cw[2][0], cw[3][0]); swap16(cw[2][1], cw[3][1]);
        s16x8 bh1[2];
        {
            u32x4 q0 = {cw[0][0], cw[0][1], cw[1][0], cw[1][1]};
            u32x4 q1 = {cw[2][0], cw[2][1], cw[3][0], cw[3][1]};
            bh1[0] = __builtin_bit_cast(s16x8, q0);
            bh1[1] = __builtin_bit_cast(s16x8, q1);
        }

        // ---- layer 2: h2^T = W2^T * h1^T + b2 (bias via broadcast LDS read) ----
        u32 cw2[8][2];
        #pragma unroll
        for (int mt = 0; mt < 8; ++mt) {
            const f32x4 c2 = *(const f32x4*)&b2f[16 * mt + bo];
            const s16x8 w2a = *(const s16x8*)&w2lds[((mt * 2 + 0) * 64 + lane) * 8];
            const s16x8 w2b = *(const s16x8*)&w2lds[((mt * 2 + 1) * 64 + lane) * 8];
            f32x4 acc2 = __builtin_amdgcn_mfma_f32_16x16x32_bf16(w2a, bh1[0], c2, 0, 0, 0);
            acc2 = __builtin_amdgcn_mfma_f32_16x16x32_bf16(w2b, bh1[1], acc2, 0, 0, 0);
            cw2[mt][0] = cvtpk(fmaxf(acc2[0], 0.f), fmaxf(acc2[1], 0.f));
            cw2[mt][1] = cvtpk(fmaxf(acc2[2], 0.f), fmaxf(acc2[3], 0.f));
        }
        #pragma unroll
        for (int m = 0; m < 8; m += 2) {
            swap32(cw2[m][0], cw2[m + 1][0]);
            swap32(cw2[m][1], cw2[m + 1][1]);
        }
        #pragma unroll
        for (int m = 0; m < 8; m += 2) {
            swap16(cw2[m][0], cw2[m + 1][0]);
            swap16(cw2[m][1], cw2[m + 1][1]);
        }
        s16x8 bh2[4];
        #pragma unroll
        for (int ks = 0; ks < 4; ++ks) {
            u32x4 q = {cw2[2 * ks][0], cw2[2 * ks][1],
                       cw2[2 * ks + 1][0], cw2[2 * ks + 1][1]};
            bh2[ks] = __builtin_bit_cast(s16x8, q);
        }

        // ---- layer 3: out^T = W3^T * h2^T + b3 (bias as C-init via LDS) ----
        f32x4 acc3[4];
        #pragma unroll
        for (int nt = 0; nt < 4; ++nt)
            acc3[nt] = *(const f32x4*)&b3f[16 * nt + bo];
        #pragma unroll
        for (int ks = 0; ks < 4; ++ks) {
            #pragma unroll
            for (int nt = 0; nt < 4; ++nt) {
                const s16x8 wf = *(const s16x8*)&w3lds[((ks * 4 + nt) * 64 + lane) * 8];
                acc3[nt] = __builtin_amdgcn_mfma_f32_16x16x32_bf16(
                    wf, bh2[ks], acc3[nt], 0, 0, 0);
            }
        }

        // ---- epilogue: relu + coalesced f32x4 stores ----
        float* const ob = out + (size_t)t * (16 * DOUT) + (size_t)cl * DOUT;
        #pragma unroll
        for (int nt = 0; nt < 4; ++nt) {
            f32x4 v;
            v[0] = fmaxf(acc3[nt][0], 0.f); v[1] = fmaxf(acc3[nt][1], 0.f);
            v[2] = fmaxf(acc3[nt][2], 0.f); v[3] = fmaxf(acc3[nt][3], 0.f);
            *(f32x4*)&ob[16 * nt + 4 * gl] = v;
        }

        t = tn;
    }
}

extern "C" void kernel_launch(void* const* d_in, const int* in_sizes, int n_in,
                              void* d_out, int out_size, void* d_ws, size_t ws_size,
                              hipStream_t stream)
{
    const float* in = (const float*)d_in[0];
    const float* W1 = (const float*)d_in[1];
    const float* b1 = (const float*)d_in[2];
    const float* W2 = (const float*)d_in[3];
    const float* b2 = (const float*)d_in[4];
    const float* W3 = (const float*)d_in[5];
    const float* b3 = (const float*)d_in[6];
    float* out = (float*)d_out;
    const int M = in_sizes[0] / DIN;

    dim3 grid(1024), block(256);  // 4 blocks/CU (36.75KB LDS, VGPR<=128) = 16 waves/CU
    hipLaunchKernelGGL(linenet_r9, grid, block, 0, stream,
                       in, W1, b1, W2, b2, W3, b3, out, M);
}

// Round 10
// 40.872 us; speedup vs baseline: 1.0038x; 1.0038x over previous
//
#include <hip/hip_runtime.h>

typedef float f32x4 __attribute__((ext_vector_type(4)));
typedef short s16x8 __attribute__((ext_vector_type(8)));
typedef unsigned int u32;
typedef unsigned int u32x4 __attribute__((ext_vector_type(4)));
typedef unsigned short u16;

#define DIN 24
#define DH1 64
#define DH2 128
#define DOUT 64

// f32 -> bf16 bits, RNE (setup path)
static __device__ __forceinline__ u16 f2bf(float f) {
    u32 u = __builtin_bit_cast(u32, f);
    u += 0x7FFFu + ((u >> 16) & 1u);
    return (u16)(u >> 16);
}
// packed f32x2 -> bf16x2, one VALU op
static __device__ __forceinline__ u32 cvtpk(float lo, float hi) {
    u32 r;
    asm("v_cvt_pk_bf16_f32 %0, %1, %2" : "=v"(r) : "v"(lo), "v"(hi));
    return r;
}
static __device__ __forceinline__ float bflo(u32 pk) {
    return __builtin_bit_cast(float, pk << 16);
}
static __device__ __forceinline__ float bfhi(u32 pk) {
    return __builtin_bit_cast(float, pk & 0xFFFF0000u);
}
// cross-lane chunk-transpose primitives (bit-exactness HW-verified in R4)
static __device__ __forceinline__ void swap32(u32& a, u32& b) {
    asm("v_permlane32_swap_b32 %0, %1" : "+v"(a), "+v"(b));
}
static __device__ __forceinline__ void swap16(u32& a, u32& b) {
    asm("v_permlane16_swap_b32 %0, %1" : "+v"(a), "+v"(b));
}

__global__ __launch_bounds__(256, 2) void linenet_r10(
    const float* __restrict__ in,
    const float* __restrict__ W1, const float* __restrict__ b1,
    const float* __restrict__ W2, const float* __restrict__ b2,
    const float* __restrict__ W3, const float* __restrict__ b3,
    float* __restrict__ out, int M)
{
    // weight fragment tables in LDS (36KB/block, R8 structure)
    __shared__ __align__(16) u16 w1lds[4 * 64 * 8];    // 4KB  (k=24 row = b1)
    __shared__ __align__(16) u16 w2lds[16 * 64 * 8];   // 16KB (frag = mt*2+ks)
    __shared__ __align__(16) u16 w3lds[16 * 64 * 8];   // 16KB (frag = ks*4+nt)

    const int tid  = threadIdx.x;
    const int lane = tid & 63;
    const int gl = lane >> 4, cl = lane & 15;

    // ---- build W1^T table ----
    {
        const int nt = tid >> 6, ln = tid & 63;
        const int g = ln >> 4, c = ln & 15;
        s16x8 v;
        #pragma unroll
        for (int j = 0; j < 8; ++j) {
            const int k = 8 * g + j;
            u16 x = 0;
            if (k < DIN)       x = f2bf(W1[k * DH1 + nt * 16 + c]);
            else if (k == DIN) x = f2bf(b1[nt * 16 + c]);
            v[j] = (short)x;
        }
        *(s16x8*)&w1lds[tid * 8] = v;
    }
    // ---- build W2^T table (frag index = mt*2+ks) ----
    for (int it = tid; it < 16 * 64; it += 256) {
        const int f = it >> 6, ln = it & 63;
        const int mt = f >> 1, ks = f & 1, g = ln >> 4, c = ln & 15;
        s16x8 v;
        #pragma unroll
        for (int j = 0; j < 8; ++j)
            v[j] = (short)f2bf(W2[(32 * ks + 8 * g + j) * DH2 + mt * 16 + c]);
        *(s16x8*)&w2lds[it * 8] = v;
    }
    // ---- build W3^T table (frag index = ks*4+nt) ----
    for (int it = tid; it < 16 * 64; it += 256) {
        const int f = it >> 6, ln = it & 63;
        const int ks = f >> 2, nt = f & 3, g = ln >> 4, c = ln & 15;
        s16x8 v;
        #pragma unroll
        for (int j = 0; j < 8; ++j)
            v[j] = (short)f2bf(W3[(32 * ks + 8 * g + j) * DOUT + nt * 16 + c]);
        *(s16x8*)&w3lds[it * 8] = v;
    }

    // ---- biases packed bf16x2 in VGPR (24 regs) ----
    u32 b2pk[8][2], b3pk[4][2];
    #pragma unroll
    for (int mt = 0; mt < 8; ++mt)
        #pragma unroll
        for (int p = 0; p < 2; ++p)
            b2pk[mt][p] = (u32)f2bf(b2[16 * mt + 4 * gl + 2 * p]) |
                          ((u32)f2bf(b2[16 * mt + 4 * gl + 2 * p + 1]) << 16);
    #pragma unroll
    for (int nt = 0; nt < 4; ++nt)
        #pragma unroll
        for (int p = 0; p < 2; ++p)
            b3pk[nt][p] = (u32)f2bf(b3[16 * nt + 4 * gl + 2 * p]) |
                          ((u32)f2bf(b3[16 * nt + 4 * gl + 2 * p + 1]) << 16);

    __syncthreads();

    const int NT = M / 16;
    const int nw = (int)gridDim.x * 4;       // 2048 waves
    int t = (int)blockIdx.x * 4 + (tid >> 6);
    if (t >= NT) return;

    const int goff = (gl < 3) ? 8 * gl : 0;
    const int loff = cl * DIN + goff;

    // dual-tile prefetch: tiles t (A) and t+nw (B)
    f32x4 pfA0, pfA1, pfB0, pfB1;
    {
        const float* p = in + (size_t)t * (16 * DIN) + loff;
        pfA0 = *(const f32x4*)p; pfA1 = *(const f32x4*)(p + 4);
        const int tB = (t + nw < NT) ? t + nw : t;
        const float* q = in + (size_t)tB * (16 * DIN) + loff;
        pfB0 = *(const f32x4*)q; pfB1 = *(const f32x4*)(q + 4);
    }

    const f32x4 zac = {0.f, 0.f, 0.f, 0.f};

    while (t < NT) {
        const int tB = (t + nw < NT) ? t + nw : t;   // tB==t only on degenerate tails

        // ---- x^T fragments for both tiles ----
        u32x4 awA, awB;
        awA[0] = cvtpk(pfA0[0], pfA0[1]); awA[1] = cvtpk(pfA0[2], pfA0[3]);
        awA[2] = cvtpk(pfA1[0], pfA1[1]); awA[3] = cvtpk(pfA1[2], pfA1[3]);
        awB[0] = cvtpk(pfB0[0], pfB0[1]); awB[1] = cvtpk(pfB0[2], pfB0[3]);
        awB[2] = cvtpk(pfB1[0], pfB1[1]); awB[3] = cvtpk(pfB1[2], pfB1[3]);
        if (gl == 3) { awA[0] = 0x00003F80u; awB[0] = 0x00003F80u; }
        const s16x8 a1A = __builtin_bit_cast(s16x8, awA);
        const s16x8 a1B = __builtin_bit_cast(s16x8, awB);

        // ---- prefetch next pair ----
        const int tn = t + 2 * nw;
        {
            const int tc  = (tn < NT) ? tn : t;
            const int tcB = (tn + nw < NT) ? tn + nw : tc;
            const float* p = in + (size_t)tc * (16 * DIN) + loff;
            pfA0 = *(const f32x4*)p; pfA1 = *(const f32x4*)(p + 4);
            const float* q = in + (size_t)tcB * (16 * DIN) + loff;
            pfB0 = *(const f32x4*)q; pfB1 = *(const f32x4*)(q + 4);
        }

        // ---- layer 1: shared weight read, two MFMAs ----
        f32x4 accA1[4], accB1[4];
        #pragma unroll
        for (int nt = 0; nt < 4; ++nt) {
            const s16x8 w1f = *(const s16x8*)&w1lds[(nt * 64 + lane) * 8];
            accA1[nt] = __builtin_amdgcn_mfma_f32_16x16x32_bf16(w1f, a1A, zac, 0, 0, 0);
            accB1[nt] = __builtin_amdgcn_mfma_f32_16x16x32_bf16(w1f, a1B, zac, 0, 0, 0);
        }

        u32 cwA[4][2], cwB[4][2];
        #pragma unroll
        for (int nt = 0; nt < 4; ++nt) {
            cwA[nt][0] = cvtpk(fmaxf(accA1[nt][0], 0.f), fmaxf(accA1[nt][1], 0.f));
            cwA[nt][1] = cvtpk(fmaxf(accA1[nt][2], 0.f), fmaxf(accA1[nt][3], 0.f));
            cwB[nt][0] = cvtpk(fmaxf(accB1[nt][0], 0.f), fmaxf(accB1[nt][1], 0.f));
            cwB[nt][1] = cvtpk(fmaxf(accB1[nt][2], 0.f), fmaxf(accB1[nt][3], 0.f));
        }
        swap32(cwA[0][0], cwA[1][0]); swap32(cwA[0][1], cwA[1][1]);
        swap32(cwA[2][0], cwA[3][0]); swap32(cwA[2][1], cwA[3][1]);
        swap16(cwA[0][0], cwA[1][0]); swap16(cwA[0][1], cwA[1][1]);
        swap16(cwA[2][0], cwA[3][0]); swap16(cwA[2][1], cwA[3][1]);
        swap32(cwB[0][0], cwB[1][0]); swap32(cwB[0][1], cwB[1][1]);
        swap32(cwB[2][0], cwB[3][0]); swap32(cwB[2][1], cwB[3][1]);
        swap16(cwB[0][0], cwB[1][0]); swap16(cwB[0][1], cwB[1][1]);
        swap16(cwB[2][0], cwB[3][0]); swap16(cwB[2][1], cwB[3][1]);
        s16x8 bh1A[2], bh1B[2];
        {
            u32x4 q0 = {cwA[0][0], cwA[0][1], cwA[1][0], cwA[1][1]};
            u32x4 q1 = {cwA[2][0], cwA[2][1], cwA[3][0], cwA[3][1]};
            bh1A[0] = __builtin_bit_cast(s16x8, q0);
            bh1A[1] = __builtin_bit_cast(s16x8, q1);
            u32x4 r0 = {cwB[0][0], cwB[0][1], cwB[1][0], cwB[1][1]};
            u32x4 r1 = {cwB[2][0], cwB[2][1], cwB[3][0], cwB[3][1]};
            bh1B[0] = __builtin_bit_cast(s16x8, r0);
            bh1B[1] = __builtin_bit_cast(s16x8, r1);
        }

        // ---- layer 2: shared weight reads, bias as C ----
        u32 cw2A[8][2], cw2B[8][2];
        #pragma unroll
        for (int mt = 0; mt < 8; ++mt) {
            f32x4 c2;
            c2[0] = bflo(b2pk[mt][0]); c2[1] = bfhi(b2pk[mt][0]);
            c2[2] = bflo(b2pk[mt][1]); c2[3] = bfhi(b2pk[mt][1]);
            const s16x8 w2a = *(const s16x8*)&w2lds[((mt * 2 + 0) * 64 + lane) * 8];
            const s16x8 w2b = *(const s16x8*)&w2lds[((mt * 2 + 1) * 64 + lane) * 8];
            f32x4 aA = __builtin_amdgcn_mfma_f32_16x16x32_bf16(w2a, bh1A[0], c2, 0, 0, 0);
            f32x4 aB = __builtin_amdgcn_mfma_f32_16x16x32_bf16(w2a, bh1B[0], c2, 0, 0, 0);
            aA = __builtin_amdgcn_mfma_f32_16x16x32_bf16(w2b, bh1A[1], aA, 0, 0, 0);
            aB = __builtin_amdgcn_mfma_f32_16x16x32_bf16(w2b, bh1B[1], aB, 0, 0, 0);
            cw2A[mt][0] = cvtpk(fmaxf(aA[0], 0.f), fmaxf(aA[1], 0.f));
            cw2A[mt][1] = cvtpk(fmaxf(aA[2], 0.f), fmaxf(aA[3], 0.f));
            cw2B[mt][0] = cvtpk(fmaxf(aB[0], 0.f), fmaxf(aB[1], 0.f));
            cw2B[mt][1] = cvtpk(fmaxf(aB[2], 0.f), fmaxf(aB[3], 0.f));
        }
        #pragma unroll
        for (int m = 0; m < 8; m += 2) {
            swap32(cw2A[m][0], cw2A[m + 1][0]); swap32(cw2A[m][1], cw2A[m + 1][1]);
            swap32(cw2B[m][0], cw2B[m + 1][0]); swap32(cw2B[m][1], cw2B[m + 1][1]);
        }
        #pragma unroll
        for (int m = 0; m < 8; m += 2) {
            swap16(cw2A[m][0], cw2A[m + 1][0]); swap16(cw2A[m][1], cw2A[m + 1][1]);
            swap16(cw2B[m][0], cw2B[m + 1][0]); swap16(cw2B[m][1], cw2B[m + 1][1]);
        }
        s16x8 bh2A[4], bh2B[4];
        #pragma unroll
        for (int ks = 0; ks < 4; ++ks) {
            u32x4 q = {cw2A[2 * ks][0], cw2A[2 * ks][1],
                       cw2A[2 * ks + 1][0], cw2A[2 * ks + 1][1]};
            bh2A[ks] = __builtin_bit_cast(s16x8, q);
            u32x4 r = {cw2B[2 * ks][0], cw2B[2 * ks][1],
                       cw2B[2 * ks + 1][0], cw2B[2 * ks + 1][1]};
            bh2B[ks] = __builtin_bit_cast(s16x8, r);
        }

        // ---- layer 3: shared weight reads, bias as C-init ----
        f32x4 accA3[4], accB3[4];
        #pragma unroll
        for (int nt = 0; nt < 4; ++nt) {
            f32x4 c3;
            c3[0] = bflo(b3pk[nt][0]); c3[1] = bfhi(b3pk[nt][0]);
            c3[2] = bflo(b3pk[nt][1]); c3[3] = bfhi(b3pk[nt][1]);
            accA3[nt] = c3; accB3[nt] = c3;
        }
        #pragma unroll
        for (int ks = 0; ks < 4; ++ks) {
            #pragma unroll
            for (int nt = 0; nt < 4; ++nt) {
                const s16x8 wf = *(const s16x8*)&w3lds[((ks * 4 + nt) * 64 + lane) * 8];
                accA3[nt] = __builtin_amdgcn_mfma_f32_16x16x32_bf16(wf, bh2A[ks], accA3[nt], 0, 0, 0);
                accB3[nt] = __builtin_amdgcn_mfma_f32_16x16x32_bf16(wf, bh2B[ks], accB3[nt], 0, 0, 0);
            }
        }

        // ---- epilogues: relu + coalesced stores (8 in flight) ----
        float* const obA = out + (size_t)t  * (16 * DOUT) + (size_t)cl * DOUT;
        float* const obB = out + (size_t)tB * (16 * DOUT) + (size_t)cl * DOUT;
        #pragma unroll
        for (int nt = 0; nt < 4; ++nt) {
            f32x4 v;
            v[0] = fmaxf(accA3[nt][0], 0.f); v[1] = fmaxf(accA3[nt][1], 0.f);
            v[2] = fmaxf(accA3[nt][2], 0.f); v[3] = fmaxf(accA3[nt][3], 0.f);
            *(f32x4*)&obA[16 * nt + 4 * gl] = v;
        }
        #pragma unroll
        for (int nt = 0; nt < 4; ++nt) {
            f32x4 v;
            v[0] = fmaxf(accB3[nt][0], 0.f); v[1] = fmaxf(accB3[nt][1], 0.f);
            v[2] = fmaxf(accB3[nt][2], 0.f); v[3] = fmaxf(accB3[nt][3], 0.f);
            *(f32x4*)&obB[16 * nt + 4 * gl] = v;
        }

        t += 2 * nw;
    }
}

extern "C" void kernel_launch(void* const* d_in, const int* in_sizes, int n_in,
                              void* d_out, int out_size, void* d_ws, size_t ws_size,
                              hipStream_t stream)
{
    const float* in = (const float*)d_in[0];
    const float* W1 = (const float*)d_in[1];
    const float* b1 = (const float*)d_in[2];
    const float* W2 = (const float*)d_in[3];
    const float* b2 = (const float*)d_in[4];
    const float* W3 = (const float*)d_in[5];
    const float* b3 = (const float*)d_in[6];
    float* out = (float*)d_out;
    const int M = in_sizes[0] / DIN;

    dim3 grid(512), block(256);   // 2 blocks/CU, dual-tile: 16 tiles in flight/CU
    hipLaunchKernelGGL(linenet_r10, grid, block, 0, stream,
                       in, W1, b1, W2, b2, W3, b3, out, M);
}